// Round 4
// baseline (85.899 us; speedup 1.0000x reference)
//
#include <hip/hip_runtime.h>

#define NPTS   4096
#define CFEAT  64
#define RADIUS_F 0.1f

// out layout (floats): grouped_xyz [2,4096,8,3] | grouped_points [2,4096,8,67] | idx [2,4096,8]
#define GX_SZ   (2*NPTS*8*3)       // 196608
#define GP_SZ   (2*NPTS*8*67)      // 4390912

__global__ __launch_bounds__(512) void pointsift_fused_kernel(
    const float* __restrict__ xyz,      // [B,4096,3]
    const float* __restrict__ points,   // [B,4096,64]
    float* __restrict__ out)
{
    __shared__ float sxyz[NPTS * 3];              // 48 KB
    __shared__ unsigned long long best[256];      // [oct][32 pts] 2 KB
    __shared__ int sj[256];                       // resolved indices, [oct][32 pts]

    const int t   = threadIdx.x;
    const int bid = blockIdx.x;
    const int b   = bid >> 7;            // batch
    const int base = (bid & 127) * 32;   // first query point of this block

    // ---- stage xyz[b] into LDS (3072 float4 / 512 threads = 6 each) ----
    {
        const float4* src = (const float4*)(xyz + (size_t)b * (NPTS * 3));
        float4* dst = (float4*)sxyz;
        #pragma unroll
        for (int e = 0; e < 6; ++e) dst[t + 512 * e] = src[t + 512 * e];
    }
    if (t < 256) best[t] = ~0ull;
    __syncthreads();

    // ---- octant-nearest search: thread = (point p, j-chunk) ----
    const int p  = t & 31;               // local point id
    const int i  = base + p;             // global query point
    const int j0 = (t >> 5) * 256;       // this thread's j-chunk
    const float xi = sxyz[i * 3 + 0];
    const float yi = sxyz[i * 3 + 1];
    const float zi = sxyz[i * 3 + 2];

    #pragma unroll 4
    for (int jj = 0; jj < 256; ++jj) {
        const int j = j0 + jj;
        const float dx = sxyz[j * 3 + 0] - xi;
        const float dy = sxyz[j * 3 + 1] - yi;
        const float dz = sxyz[j * 3 + 2] - zi;
        if (fmaxf(fabsf(dx), fmaxf(fabsf(dy), fabsf(dz))) < RADIUS_F) {
            // match XLA: separate f32 mul/add, no contraction
            const float dist = __fadd_rn(__fadd_rn(__fmul_rn(dx, dx), __fmul_rn(dy, dy)),
                                         __fmul_rn(dz, dz));
            const int oct = ((dx > 0.f) ? 4 : 0) | ((dy > 0.f) ? 2 : 0) | ((dz > 0.f) ? 1 : 0);
            const unsigned long long key =
                ((unsigned long long)__float_as_uint(dist) << 32) | (unsigned int)j;
            atomicMin(&best[(oct << 5) | p], key);   // lexicographic (dist, j) min == argmin
        }
    }
    __syncthreads();

    float* gx_out  = out;                 // [B,N,8,3]
    float* gp_out  = out + GX_SZ;         // [B,N,8,67]
    float* idx_out = out + GX_SZ + GP_SZ; // [B,N,8] as float

    // ---- epilogue A: resolve idx, write idx + grouped_xyz + gp[0:3] ----
    if (t < 256) {
        const int o  = t & 7;            // octant  (coalesced g mapping)
        const int pp = t >> 3;           // local point
        const int ii = base + pp;
        const unsigned long long key = best[(o << 5) | pp];
        const int j = (key == ~0ull) ? ii : (int)(unsigned int)(key & 0xFFFFFFFFull);
        sj[(o << 5) | pp] = j;
        const size_t g = ((size_t)(b * NPTS + ii) << 3) + o;   // (b,i,o) row id
        const float gx = sxyz[j * 3 + 0] - sxyz[ii * 3 + 0];
        const float gy = sxyz[j * 3 + 1] - sxyz[ii * 3 + 1];
        const float gz = sxyz[j * 3 + 2] - sxyz[ii * 3 + 2];
        gx_out[g * 3 + 0] = gx;
        gx_out[g * 3 + 1] = gy;
        gx_out[g * 3 + 2] = gz;
        gp_out[g * 67 + 0] = gx;
        gp_out[g * 67 + 1] = gy;
        gp_out[g * 67 + 2] = gz;
        idx_out[g] = (float)j;
    }
    __syncthreads();

    // ---- epilogue B: gather features, wave wv handles octant wv ----
    const int wv   = t >> 6;             // 0..7 == octant
    const int lane = t & 63;
    const float* pbase = points + (size_t)b * (NPTS * CFEAT);
    for (int q = 0; q < 32; ++q) {
        const int j  = sj[(wv << 5) + q];
        const int ii = base + q;
        const size_t g = ((size_t)(b * NPTS + ii) << 3) + wv;
        gp_out[g * 67 + 3 + lane] = pbase[(size_t)j * CFEAT + lane];  // coalesced 256B row
    }
}

extern "C" void kernel_launch(void* const* d_in, const int* in_sizes, int n_in,
                              void* d_out, int out_size, void* d_ws, size_t ws_size,
                              hipStream_t stream) {
    const float* xyz    = (const float*)d_in[0];   // [2,4096,3]
    const float* points = (const float*)d_in[1];   // [2,4096,64]
    float* out = (float*)d_out;
    pointsift_fused_kernel<<<256, 512, 0, stream>>>(xyz, points, out);
}

// Round 7
// 78.960 us; speedup vs baseline: 1.0879x; 1.0879x over previous
//
#include <hip/hip_runtime.h>

#define NPTS   4096
#define CFEAT  64
#define RADIUS_F 0.1f

// out layout (floats): grouped_xyz [2,4096,8,3] | grouped_points [2,4096,8,67] | idx [2,4096,8]
#define GX_SZ   (2*NPTS*8*3)       // 196608
#define GP_SZ   (2*NPTS*8*67)      // 4390912

__global__ __launch_bounds__(512) void pointsift_fused_kernel(
    const float* __restrict__ xyz,      // [B,4096,3]
    const float* __restrict__ points,   // [B,4096,64]
    float* __restrict__ out)
{
    __shared__ float sxyz[NPTS * 3];              // 48 KB
    __shared__ unsigned long long best[256];      // [oct][32 pts] 2 KB
    __shared__ int sj[256];                       // resolved indices, [oct][32 pts]

    const int t   = threadIdx.x;
    const int bid = blockIdx.x;
    const int b   = bid >> 7;            // batch
    const int base = (bid & 127) * 32;   // first query point of this block

    // ---- stage xyz[b] into LDS (3072 float4 / 512 threads = 6 each) ----
    {
        const float4* src = (const float4*)(xyz + (size_t)b * (NPTS * 3));
        float4* dst = (float4*)sxyz;
        #pragma unroll
        for (int e = 0; e < 6; ++e) dst[t + 512 * e] = src[t + 512 * e];
    }
    if (t < 256) best[t] = ~0ull;
    __syncthreads();

    // ---- octant-nearest search, register-blocked: thread = (4 queries, 1 j/iter) ----
    // wave reads 8 CONSECUTIVE j (stride 12B -> distinct banks, 8-way broadcast);
    // each j tested against 4 register-resident queries => 4x fewer LDS instrs.
    const int lane = t & 63;
    const int wv   = t >> 6;             // wave 0..7, owns j-range [wv*512, wv*512+512)
    const int jo   = lane & 7;           // j offset within 8-j group
    const int qg   = lane >> 3;          // query group 0..7
    const int q0   = qg * 4;             // first of this thread's 4 queries

    float qx[4], qy[4], qz[4];
    #pragma unroll
    for (int s = 0; s < 4; ++s) {
        const int i = base + q0 + s;
        qx[s] = sxyz[i * 3 + 0];
        qy[s] = sxyz[i * 3 + 1];
        qz[s] = sxyz[i * 3 + 2];
    }

    const int jstart = wv * 512 + jo;
    #pragma unroll 2
    for (int it = 0; it < 64; ++it) {
        const int j = jstart + it * 8;
        const float px = sxyz[j * 3 + 0];
        const float py = sxyz[j * 3 + 1];
        const float pz = sxyz[j * 3 + 2];
        #pragma unroll
        for (int s = 0; s < 4; ++s) {
            const float dx = px - qx[s];
            const float dy = py - qy[s];
            const float dz = pz - qz[s];
            if (fmaxf(fabsf(dx), fmaxf(fabsf(dy), fabsf(dz))) < RADIUS_F) {
                // match XLA: separate f32 mul/add, no contraction (argmin tie safety)
                const float dist = __fadd_rn(__fadd_rn(__fmul_rn(dx, dx), __fmul_rn(dy, dy)),
                                             __fmul_rn(dz, dz));
                const int oct = ((dx > 0.f) ? 4 : 0) | ((dy > 0.f) ? 2 : 0) | ((dz > 0.f) ? 1 : 0);
                const unsigned long long key =
                    ((unsigned long long)__float_as_uint(dist) << 32) | (unsigned int)j;
                atomicMin(&best[(oct << 5) | (q0 + s)], key);  // lex (dist, j) min == argmin
            }
        }
    }
    __syncthreads();

    float* gx_out  = out;                 // [B,N,8,3]
    float* gp_out  = out + GX_SZ;         // [B,N,8,67]
    float* idx_out = out + GX_SZ + GP_SZ; // [B,N,8] as float

    // ---- epilogue A: resolve idx, write idx + grouped_xyz + gp[0:3] ----
    if (t < 256) {
        const int o  = t & 7;            // octant  (coalesced g mapping)
        const int pp = t >> 3;           // local point
        const int ii = base + pp;
        const unsigned long long key = best[(o << 5) | pp];
        const int j = (key == ~0ull) ? ii : (int)(unsigned int)(key & 0xFFFFFFFFull);
        sj[(o << 5) | pp] = j;
        const size_t g = ((size_t)(b * NPTS + ii) << 3) + o;   // (b,i,o) row id
        const float gx = sxyz[j * 3 + 0] - sxyz[ii * 3 + 0];
        const float gy = sxyz[j * 3 + 1] - sxyz[ii * 3 + 1];
        const float gz = sxyz[j * 3 + 2] - sxyz[ii * 3 + 2];
        gx_out[g * 3 + 0] = gx;
        gx_out[g * 3 + 1] = gy;
        gx_out[g * 3 + 2] = gz;
        gp_out[g * 67 + 0] = gx;
        gp_out[g * 67 + 1] = gy;
        gp_out[g * 67 + 2] = gz;
        idx_out[g] = (float)j;
    }
    __syncthreads();

    // ---- epilogue B: gather features, wave wv handles octant wv ----
    const float* pbase = points + (size_t)b * (NPTS * CFEAT);
    for (int q = 0; q < 32; ++q) {
        const int j  = sj[(wv << 5) + q];
        const int ii = base + q;
        const size_t g = ((size_t)(b * NPTS + ii) << 3) + wv;
        gp_out[g * 67 + 3 + lane] = pbase[(size_t)j * CFEAT + lane];  // coalesced 256B row
    }
}

extern "C" void kernel_launch(void* const* d_in, const int* in_sizes, int n_in,
                              void* d_out, int out_size, void* d_ws, size_t ws_size,
                              hipStream_t stream) {
    const float* xyz    = (const float*)d_in[0];   // [2,4096,3]
    const float* points = (const float*)d_in[1];   // [2,4096,64]
    float* out = (float*)d_out;
    pointsift_fused_kernel<<<256, 512, 0, stream>>>(xyz, points, out);
}